// Round 10
// baseline (258.160 us; speedup 1.0000x reference)
//
#include <hip/hip_runtime.h>
#include <hip/hip_bf16.h>
#include <cstdint>
#include <cstddef>

#define SEQ_N 2048
#define DIM   1024
#define NHEAD 16
#define DH    64

typedef __bf16 bf16;
typedef __attribute__((ext_vector_type(8))) __bf16 bf16x8;
typedef __attribute__((ext_vector_type(4))) __bf16 bf16x4;
typedef __attribute__((ext_vector_type(4))) float f32x4;

// async global->LDS 16B copy: LDS dest = wave-uniform base + lane*16
__device__ __forceinline__ void gl_lds16(const bf16* g, bf16* l) {
    __builtin_amdgcn_global_load_lds(
        (const __attribute__((address_space(1))) unsigned int*)g,
        (__attribute__((address_space(3))) unsigned int*)l, 16, 0, 0);
}

// ---------------------------------------------------------------------------
// prep: fused input cast (x, pos -> bf16) + all weight transposes.
// ---------------------------------------------------------------------------
__global__ __launch_bounds__(256) void prep_kernel(
    const float* __restrict__ x, const float* __restrict__ pos,
    const float* __restrict__ Wq, const float* __restrict__ Wkv,
    const float* __restrict__ Wo, const float* __restrict__ Wp,
    bf16* __restrict__ xb, bf16* __restrict__ posb,
    bf16* __restrict__ WqkvT, bf16* __restrict__ WoT, bf16* __restrict__ WpT)
{
    int bid = blockIdx.x;
    if (bid < 6144) {
        const int NX = 4096 * 1024;
        int i = (bid * 256 + threadIdx.x) * 4;
        if (i < NX) {
            float4 v = *(const float4*)&x[i];
            xb[i + 0] = (bf16)v.x; xb[i + 1] = (bf16)v.y;
            xb[i + 2] = (bf16)v.z; xb[i + 3] = (bf16)v.w;
        } else {
            int j = i - NX;
            float4 v = *(const float4*)&pos[j];
            posb[j + 0] = (bf16)v.x; posb[j + 1] = (bf16)v.y;
            posb[j + 2] = (bf16)v.z; posb[j + 3] = (bf16)v.w;
        }
        return;
    }
    __shared__ float t[32][33];
    bid -= 6144;
    const float* src; bf16* dst; int tidx, nx, N;
    if (bid < 1024)      { src = Wq;  dst = WqkvT;                       tidx = bid;        nx = 32; N = 1024; }
    else if (bid < 3072) { src = Wkv; dst = WqkvT + (size_t)1024 * 1024; tidx = bid - 1024; nx = 64; N = 2048; }
    else if (bid < 4096) { src = Wo;  dst = WoT;                         tidx = bid - 3072; nx = 32; N = 1024; }
    else                 { src = Wp;  dst = WpT;                         tidx = bid - 4096; nx = 2;  N = 64;   }
    int n0 = (tidx % nx) * 32, k0 = (tidx / nx) * 32;
    int tx = threadIdx.x & 31, ty = threadIdx.x >> 5;
    #pragma unroll
    for (int r = ty; r < 32; r += 8)
        t[r][tx] = src[(size_t)(k0 + r) * N + n0 + tx];
    __syncthreads();
    #pragma unroll
    for (int r = ty; r < 32; r += 8)
        dst[(size_t)(n0 + r) * 1024 + k0 + tx] = (bf16)t[tx][r];
}

// ---------------------------------------------------------------------------
// qkv projection + p projection, one dispatch. grid (25, 32).
// q output PRE-SCALED by 0.125*log2(e): folds attn scale + exp->exp2 (exact).
// ---------------------------------------------------------------------------
__global__ __launch_bounds__(256) void qkvp_kernel(
    const bf16* __restrict__ xb, const bf16* __restrict__ WqkvT,
    const bf16* __restrict__ posb, const bf16* __restrict__ WpT,
    const float* __restrict__ bq, const float* __restrict__ bkv,
    const float* __restrict__ bp,
    bf16* __restrict__ qbuf, bf16* __restrict__ kbuf,
    bf16* __restrict__ vtbuf, bf16* __restrict__ pfrag)
{
    __shared__ __align__(16) bf16 sm[128 * 132];   // At|Bt staging / V bounce
    bf16* At = sm;
    bf16* Bt = sm + 128 * 64;
    const int tid = threadIdx.x, w = tid >> 6, lane = tid & 63;
    const int q = lane >> 4, ln15 = lane & 15;
    const int lr = lane >> 3, c_log = (lane & 7) ^ lr;
    const int bx = blockIdx.x, by = blockIdx.y;
    const int m0 = by * 128;

    if (bx == 24) {
        if (by >= 16) return;
        f32x4 acc[2][4] = {};
        for (int k0 = 0; k0 < 1024; k0 += 64) {
            __syncthreads();
            #pragma unroll
            for (int t = 0; t < 4; ++t)
                gl_lds16(&posb[(size_t)(m0 + 32 * w + 8 * t + lr) * 1024 + k0 + c_log * 8],
                         &At[(32 * w + 8 * t) * 64]);
            #pragma unroll
            for (int t = 0; t < 2; ++t)
                gl_lds16(&WpT[(size_t)(16 * w + 8 * t + lr) * 1024 + k0 + c_log * 8],
                         &Bt[(16 * w + 8 * t) * 64]);
            __syncthreads();
            bf16x8 bfr[2][4];
            #pragma unroll
            for (int ks = 0; ks < 2; ++ks)
                #pragma unroll
                for (int sn = 0; sn < 4; ++sn) {
                    int rb = 16 * sn + ln15;
                    bfr[ks][sn] = *(const bf16x8*)&Bt[(rb * 8 + ((4 * ks + q) ^ (rb & 7))) * 8];
                }
            #pragma unroll
            for (int sm2 = 0; sm2 < 2; ++sm2) {
                int ra = 32 * w + 16 * sm2 + ln15;
                #pragma unroll
                for (int ks = 0; ks < 2; ++ks) {
                    bf16x8 af = *(const bf16x8*)&At[(ra * 8 + ((4 * ks + q) ^ (ra & 7))) * 8];
                    #pragma unroll
                    for (int sn = 0; sn < 4; ++sn)
                        acc[sm2][sn] = __builtin_amdgcn_mfma_f32_16x16x32_bf16(
                            af, bfr[ks][sn], acc[sm2][sn], 0, 0, 0);
                }
            }
        }
        #pragma unroll
        for (int sm2 = 0; sm2 < 2; ++sm2)
            #pragma unroll
            for (int sn = 0; sn < 4; ++sn)
                #pragma unroll
                for (int r = 0; r < 4; ++r) {
                    int row = m0 + 32 * w + 16 * sm2 + 4 * q + r;
                    int d = 16 * sn + ln15;
                    int sb = row >> 4, lnp = row & 15;
                    int ks2 = d >> 5, qd = (d >> 3) & 3, e = d & 7;
                    pfrag[(((size_t)sb * 2 + ks2) * 64 + qd * 16 + lnp) * 8 + e] =
                        (bf16)(acc[sm2][sn][r] + bp[d]);
                }
        return;
    }

    // ---- qkv GEMM tile ----
    const int n0 = bx * 128;
    const int wm = w >> 1, wn = w & 1;
    f32x4 acc[4][4] = {};

    for (int k0 = 0; k0 < 1024; k0 += 64) {
        __syncthreads();
        #pragma unroll
        for (int t = 0; t < 4; ++t) {
            int r = 32 * w + 8 * t + lr;
            gl_lds16(&xb[(size_t)(m0 + r) * 1024 + k0 + c_log * 8],
                     &At[(32 * w + 8 * t) * 64]);
            gl_lds16(&WqkvT[(size_t)(n0 + r) * 1024 + k0 + c_log * 8],
                     &Bt[(32 * w + 8 * t) * 64]);
        }
        __syncthreads();

        bf16x8 af[2][4], bfr[2][4];
        #pragma unroll
        for (int ks = 0; ks < 2; ++ks)
            #pragma unroll
            for (int s = 0; s < 4; ++s) {
                int ra = 64 * wm + 16 * s + ln15;
                af[ks][s]  = *(const bf16x8*)&At[(ra * 8 + ((4 * ks + q) ^ (ra & 7))) * 8];
                int rb = 64 * wn + 16 * s + ln15;
                bfr[ks][s] = *(const bf16x8*)&Bt[(rb * 8 + ((4 * ks + q) ^ (rb & 7))) * 8];
            }
        #pragma unroll
        for (int ks = 0; ks < 2; ++ks)
            #pragma unroll
            for (int si = 0; si < 4; ++si)
                #pragma unroll
                for (int sj = 0; sj < 4; ++sj)
                    acc[si][sj] = __builtin_amdgcn_mfma_f32_16x16x32_bf16(
                        af[ks][si], bfr[ks][sj], acc[si][sj], 0, 0, 0);
    }

    if (bx < 16) {
        // q (pre-scaled) / k natural layout
        const float QSCL = 0.125f * 1.44269504088896341f;
        #pragma unroll
        for (int si = 0; si < 4; ++si)
            #pragma unroll
            for (int sj = 0; sj < 4; ++sj)
                #pragma unroll
                for (int r = 0; r < 4; ++r) {
                    int row = m0 + 64 * wm + 16 * si + 4 * q + r;
                    int col = n0 + 64 * wn + 16 * sj + ln15;
                    float v = acc[si][sj][r] + (col < 1024 ? bq[col] : bkv[col - 1024]);
                    if (col < 1024) qbuf[(size_t)row * 1024 + col] = (bf16)(v * QSCL);
                    else            kbuf[(size_t)row * 1024 + (col - 1024)] = (bf16)v;
                }
    } else {
        // V: transpose to (b,h,d,t) via LDS bounce, 16B coalesced stores
        __syncthreads();   // all waves done reading At/Bt
        #pragma unroll
        for (int si = 0; si < 4; ++si)
            #pragma unroll
            for (int sj = 0; sj < 4; ++sj) {
                int dL = 64 * wn + 16 * sj + ln15;        // 0..127
                int tL = 64 * wm + 16 * si + 4 * q;       // +r
                float bias = bkv[1024 + (bx - 16) * 128 + dL];
                bf16x4 o4;
                #pragma unroll
                for (int r = 0; r < 4; ++r)
                    o4[r] = (bf16)(acc[si][sj][r] + bias);
                *(bf16x4*)&sm[dL * 132 + tL] = o4;
            }
        __syncthreads();
        const int b = m0 >> 11;
        const int t0 = m0 & 2047;
        const int h0 = (bx - 16) * 2;
        #pragma unroll
        for (int p = 0; p < 16; ++p) {
            int d = (tid >> 5) + 8 * p;
            int t = (tid & 31) * 4;
            bf16x4 v4 = *(const bf16x4*)&sm[d * 132 + t];
            int rowv = (b * NHEAD + h0 + (d >> 6)) * DH + (d & 63);
            *(bf16x4*)&vtbuf[(size_t)rowv * SEQ_N + t0 + t] = v4;
        }
    }
}

// ---------------------------------------------------------------------------
// MFMA flash attention, KVBLK=128 round.
//   Evidence R1/R6/R8/R9: time/CU-iteration ~1.3us invariant to concurrency
//   (2..6 resident) and DS traffic; no pipe >40% -> fixed per-iteration
//   serial overhead (2 barriers + softmax passes + load-waits) dominates.
//   This round HALVES the iteration count: 128-wide KV tiles.
//   - per KV element: barriers x0.5, softmax max/sum/rescale passes x0.5,
//     loop overhead x0.5; MFMA/LDS/fetch per element unchanged.
//   - S2 ring extends to 8 subtiles/iter (identical sb sequence + carry as
//     two 64-steps -> bit-exact); S2L 16x148/wave, written subtile-at-a-time
//     to cap VGPR. Pw 16x128 aliased onto S2L.
//   - diagonal mask: jl > ((qblk&1)<<6) + il; odd tails mask-handled (P=0).
//   - LDS: S2L 9472 + Ks 128x64 + Vs 64x128 = 51,712 B -> 3 blocks/CU
//     (residency is NOT the lever per R6-R9; no launch-bounds squeeze, R7).
//   Decode identical to R8 (bijective, part0/part1/whole), loop bounds
//   converted: lo128 = lo64/2, hi128 = ceil(hi64/2).
// ---------------------------------------------------------------------------
__global__ __launch_bounds__(256, 4) void attn_mfma_kernel(
    const bf16* __restrict__ qb,    // [4096][1024], pre-scaled
    const bf16* __restrict__ kb,    // [4096][1024]
    const bf16* __restrict__ vt,    // [(b,h,d)][2048]
    const bf16* __restrict__ pfrag, // fragment-ready p
    bf16* __restrict__ ob,          // [4096][1024]
    float* __restrict__ Opart,      // [1024][64][64] fp32 partials
    float2* __restrict__ MLpart)    // [1024][64] (m,l)
{
    // ---- block decode (R8): f -> (bh, qblk, [lo,hi) in 64-tiles, part) ----
    const int f   = (int)blockIdx.x;   // 0..1535
    const int xcd = f & 7;
    const int jj  = f >> 3;            // 0..191
    const int c   = jj & 31;
    const int rr  = jj >> 5;           // 0..5
    const int bh  = xcd * 4 + (c & 3);
    const int g   = c >> 2;            // 0..7
    int qblk, lo64, hi64, part;        // part: -1 single, 0/1 split halves
    switch (rr) {
        case 0:  qblk = 16 + 2 * g; lo64 = 0;  hi64 = 16;       part = 0;  break;
        case 1:  qblk = 17 + 2 * g; lo64 = 0;  hi64 = 16;       part = 0;  break;
        case 2:  qblk = 31 - g;     lo64 = 16; hi64 = qblk + 1; part = 1;  break;
        case 3:  qblk = 16 + g;     lo64 = 16; hi64 = qblk + 1; part = 1;  break;
        case 4:  qblk = 15 - g;     lo64 = 0;  hi64 = qblk + 1; part = -1; break;
        default: qblk = g;          lo64 = 0;  hi64 = qblk + 1; part = -1; break;
    }
    const int lo = lo64 >> 1;          // 128-tile units (0 or 8)
    const int hi = (hi64 + 1) >> 1;    // ceil
    const int bi = bh >> 4, hh = bh & 15;
    const int i0 = qblk << 6;
    const int tid = threadIdx.x, w = tid >> 6, lane = tid & 63;
    const int q = lane >> 4, ln15 = lane & 15;
    const int lr = lane >> 3, c_log = (lane & 7) ^ lr;
    const bool hasDiag = (part != 0);
    const int moff = ((qblk & 1) << 6) + 16 * w + ln15;  // diag mask threshold

    // 51,712 B: per-wave S2L (16x148, Pw 16x128 aliased) + Ks 128x64 + Vs 64x128
    __shared__ __align__(16) bf16 smem[25856];
    bf16* S2L = smem + w * 2368;           // per-wave, [0,9472)
    bf16* Pw  = smem + w * 2368;           // ALIAS (time-disjoint)
    bf16* Ks  = smem + 9472;               // 128x64 swizzled
    bf16* Vs  = smem + 17664;              // 64x128 swizzled

    const bf16* qbase = qb + ((size_t)(bi * SEQ_N + i0)) * DIM + hh * DH;
    const bf16* kbase = kb + ((size_t)bi * SEQ_N) * DIM + hh * DH;
    const bf16* vbase = vt + ((size_t)(bi * NHEAD + hh) * DH) * SEQ_N;

    // ---- prologue: Q fragments direct from global (pre-scaled) ----
    bf16x8 qf0 = *(const bf16x8*)&qbase[(size_t)(16 * w + ln15) * DIM + q * 8];
    bf16x8 qf1 = *(const bf16x8*)&qbase[(size_t)(16 * w + ln15) * DIM + 32 + q * 8];

    const int A0 = 127 - 4 * qblk - w;
    f32x4 s2r4;   // carry = subtile sb = A0 + 8*jt (ss=0 of current window)
    {
        int sb0 = A0 + 8 * lo;
        bf16x8 f0 = *(const bf16x8*)&pfrag[(((size_t)sb0 * 2 + 0) * 64 + lane) * 8];
        bf16x8 f1 = *(const bf16x8*)&pfrag[(((size_t)sb0 * 2 + 1) * 64 + lane) * 8];
        f32x4 a = {0.f, 0.f, 0.f, 0.f};
        a = __builtin_amdgcn_mfma_f32_16x16x32_bf16(f0, qf0, a, 0, 0, 0);
        a = __builtin_amdgcn_mfma_f32_16x16x32_bf16(f1, qf1, a, 0, 0, 0);
        s2r4 = a;
    }

    float m_run = -1e30f, l_run = 0.f;
    f32x4 O_T[4] = {};

    for (int jt = lo; jt < hi; ++jt) {
        const int j0 = jt << 7;

        // [2] stage K (128x64) + V (64x128), async DMA
        #pragma unroll
        for (int t = 0; t < 4; ++t)
            gl_lds16(kbase + (size_t)(j0 + 32 * w + 8 * t + lr) * DIM + c_log * 8,
                     &Ks[(32 * w + 8 * t) * 64]);
        #pragma unroll
        for (int t = 0; t < 4; ++t) {
            int rv_ = 16 * w + 4 * t + (lane >> 4);
            int cs  = (lane & 15) ^ (rv_ & 7);
            gl_lds16(vbase + (size_t)rv_ * SEQ_N + j0 + cs * 8,
                     &Vs[(16 * w + 4 * t) * 128]);
        }

        // [3] S2(jt): 8 subtiles + carry, write-as-you-go (covers gl_lds)
        {
            bf16x4 v4;
            #pragma unroll
            for (int r = 0; r < 4; ++r)
                v4[r] = (bf16)s2r4[r];
            *(bf16x4*)&S2L[ln15 * 148 + 4 * q] = v4;
            #pragma unroll
            for (int ss = 1; ss <= 8; ++ss) {
                int sb = A0 + 8 * jt + ss;
                if (sb > 127) sb = 127;
                bf16x8 f0 = *(const bf16x8*)&pfrag[(((size_t)sb * 2 + 0) * 64 + lane) * 8];
                bf16x8 f1 = *(const bf16x8*)&pfrag[(((size_t)sb * 2 + 1) * 64 + lane) * 8];
                f32x4 a = {0.f, 0.f, 0.f, 0.f};
                a = __builtin_amdgcn_mfma_f32_16x16x32_bf16(f0, qf0, a, 0, 0, 0);
                a = __builtin_amdgcn_mfma_f32_16x16x32_bf16(f1, qf1, a, 0, 0, 0);
                #pragma unroll
                for (int r = 0; r < 4; ++r)
                    v4[r] = (bf16)a[r];
                *(bf16x4*)&S2L[ln15 * 148 + 16 * ss + 4 * q] = v4;
                if (ss == 8) s2r4 = a;
            }
        }

        __syncthreads();

        // [4] QK^T over 128 cols, bias as C-init (exp2-domain)
        float sv[8][4];
        __builtin_amdgcn_s_setprio(1);
        #pragma unroll
        for (int sn = 0; sn < 8; ++sn) {
            int rk = 16 * sn + ln15;
            bf16x8 k0f = *(const bf16x8*)&Ks[(rk * 8 + ((q    ) ^ (rk & 7))) * 8];
            bf16x8 k1f = *(const bf16x8*)&Ks[(rk * 8 + ((4 + q) ^ (rk & 7))) * 8];
            f32x4 a;
            #pragma unroll
            for (int r = 0; r < 4; ++r)
                a[r] = (float)S2L[ln15 * 148 + 15 - ln15 + 16 * sn + 4 * q + r];
            a = __builtin_amdgcn_mfma_f32_16x16x32_bf16(k0f, qf0, a, 0, 0, 0);
            a = __builtin_amdgcn_mfma_f32_16x16x32_bf16(k1f, qf1, a, 0, 0, 0);
            #pragma unroll
            for (int r = 0; r < 4; ++r)
                sv[sn][r] = a[r];
        }
        __builtin_amdgcn_s_setprio(0);
        if (hasDiag && jt == hi - 1) {
            #pragma unroll
            for (int sn = 0; sn < 8; ++sn)
                #pragma unroll
                for (int r = 0; r < 4; ++r)
                    if (16 * sn + 4 * q + r > moff)
                        sv[sn][r] = -1e30f;
        }

        // [5] online softmax over 128 cols (one pass per 128 KV)
        float mx = sv[0][0];
        #pragma unroll
        for (int sn = 0; sn < 8; ++sn)
            #pragma unroll
            for (int r = 0; r < 4; ++r)
                mx = fmaxf(mx, sv[sn][r]);
        mx = fmaxf(mx, __shfl_xor(mx, 16));
        mx = fmaxf(mx, __shfl_xor(mx, 32));
        const float mn = fmaxf(m_run, mx);
        float sum = 0.f;
        #pragma unroll
        for (int sn = 0; sn < 8; ++sn)
            #pragma unroll
            for (int r = 0; r < 4; ++r) {
                float e = exp2f(sv[sn][r] - mn);
                sv[sn][r] = e;
                sum += e;
            }
        sum += __shfl_xor(sum, 16);
        sum += __shfl_xor(sum, 32);
        if (__all(mx <= m_run)) {
            l_run += sum;                       // alpha == 1 exactly
        } else {
            const float alpha = exp2f(m_run - mn);
            l_run = l_run * alpha + sum;
            #pragma unroll
            for (int sd = 0; sd < 4; ++sd)
                #pragma unroll
                for (int r = 0; r < 4; ++r)
                    O_T[sd][r] *= alpha;
        }
        m_run = mn;

        // [6] P -> Pw (aliases S2L, consumed at [4]): 8x ds_write_b64
        #pragma unroll
        for (int sn = 0; sn < 8; ++sn) {
            int chunk = (2 * sn + (q >> 1)) ^ (ln15 & 7);
            bf16x4 v4;
            #pragma unroll
            for (int r = 0; r < 4; ++r)
                v4[r] = (bf16)sv[sn][r];
            *(bf16x4*)&Pw[ln15 * 128 + chunk * 8 + 4 * (q & 1)] = v4;
        }

        __builtin_amdgcn_s_waitcnt(0);

        // [7] PV over K=128: 4 ks-slots x 4 sd
        __builtin_amdgcn_s_setprio(1);
        #pragma unroll
        for (int ks = 0; ks < 4; ++ks) {
            bf16x8 pT = *(const bf16x8*)&Pw[ln15 * 128 + (((4 * ks + q) ^ (ln15 & 7))) * 8];
            #pragma unroll
            for (int sd = 0; sd < 4; ++sd) {
                int rv = 16 * sd + ln15;
                bf16x8 vf = *(const bf16x8*)&Vs[rv * 128 + (((4 * ks + q) ^ (rv & 7))) * 8];
                O_T[sd] = __builtin_amdgcn_mfma_f32_16x16x32_bf16(vf, pT, O_T[sd], 0, 0, 0);
            }
        }
        __builtin_amdgcn_s_setprio(0);
        __syncthreads();
    }

    const int row = 16 * w + ln15;
    if (part < 0) {
        // complete block: normalize and write bf16 output
        const float inv = 1.0f / l_run;
        const size_t grow = (size_t)bi * SEQ_N + i0 + row;
        #pragma unroll
        for (int sd = 0; sd < 4; ++sd) {
            bf16x4 o4;
            #pragma unroll
            for (int r = 0; r < 4; ++r)
                o4[r] = (bf16)(O_T[sd][r] * inv);
            *(bf16x4*)&ob[grow * DIM + hh * DH + 16 * sd + 4 * q] = o4;
        }
    } else {
        // split part: write un-normalized fp32 O + (m,l) for the merge
        const int slot = (bh * 16 + (qblk - 16)) * 2 + part;
        float* op = Opart + (size_t)slot * 4096 + row * 64;
        #pragma unroll
        for (int sd = 0; sd < 4; ++sd)
            *(f32x4*)&op[16 * sd + 4 * q] = O_T[sd];
        if (lane < 16)
            MLpart[slot * 64 + row] = make_float2(m_run, l_run);
    }
}

// ---------------------------------------------------------------------------
// merge: combine the two KV-half partials of each qblk>=16 row-block.
// Exact online-softmax merge (exp2 domain). 512 blocks x 256 threads.
// ---------------------------------------------------------------------------
__global__ __launch_bounds__(256) void merge_kernel(
    const float* __restrict__ Opart, const float2* __restrict__ MLpart,
    bf16* __restrict__ ob)
{
    const int pb = blockIdx.x;             // 0..511
    const int bh = pb >> 4, qblk = 16 + (pb & 15);
    const int bi = bh >> 4, hh = bh & 15;
    const int row = threadIdx.x >> 2;
    const int d0 = (threadIdx.x & 3) * 16;

    float2 ml0 = MLpart[(pb * 2 + 0) * 64 + row];
    float2 ml1 = MLpart[(pb * 2 + 1) * 64 + row];
    float m = fmaxf(ml0.x, ml1.x);
    float a0 = exp2f(ml0.x - m), a1 = exp2f(ml1.x - m);
    float inv = 1.0f / (ml0.y * a0 + ml1.y * a1);

    const float* o0 = Opart + ((size_t)(pb * 2 + 0)) * 4096 + row * 64 + d0;
    const float* o1 = Opart + ((size_t)(pb * 2 + 1)) * 4096 + row * 64 + d0;
    bf16* dst = ob + ((size_t)(bi * SEQ_N + qblk * 64 + row)) * DIM + hh * DH + d0;
    #pragma unroll
    for (int k = 0; k < 4; ++k) {
        float4 v0 = *(const float4*)&o0[4 * k];
        float4 v1 = *(const float4*)&o1[4 * k];
        bf16x4 o4;
        o4[0] = (bf16)((v0.x * a0 + v1.x * a1) * inv);
        o4[1] = (bf16)((v0.y * a0 + v1.y * a1) * inv);
        o4[2] = (bf16)((v0.z * a0 + v1.z * a1) * inv);
        o4[3] = (bf16)((v0.w * a0 + v1.w * a1) * inv);
        *(bf16x4*)&dst[4 * k] = o4;
    }
}

// ---------------------------------------------------------------------------
// out = abuf @ WoT^T + bo, fp32 out. 128x64 tiles -> grid (16,32), 2/CU.
// ---------------------------------------------------------------------------
__global__ __launch_bounds__(256) void outproj_kernel(
    const bf16* __restrict__ ab, const bf16* __restrict__ WoT,
    const float* __restrict__ bo, float* __restrict__ out)
{
    __shared__ __align__(16) bf16 At[128 * 64];
    __shared__ __align__(16) bf16 Bt[64 * 64];
    const int tid = threadIdx.x, w = tid >> 6, lane = tid & 63;
    const int q = lane >> 4, ln15 = lane & 15;
    const int lr = lane >> 3, c_log = (lane & 7) ^ lr;
    const int m0 = blockIdx.y * 128, n0 = blockIdx.x * 64;

    f32x4 acc[2][4] = {};
    for (int k0 = 0; k0 < 1024; k0 += 64) {
        __syncthreads();
        #pragma unroll
        for (int t = 0; t < 4; ++t)
            gl_lds16(&ab[(size_t)(m0 + 32 * w + 8 * t + lr) * 1024 + k0 + c_log * 8],
                     &At[(32 * w + 8 * t) * 64]);
        #pragma unroll
        for (int t = 0; t < 2; ++t)
            gl_lds16(&WoT[(size_t)(n0 + 16 * w + 8 * t + lr) * 1024 + k0 + c_log * 8],
                     &Bt[(16 * w + 8 * t) * 64]);
        __syncthreads();

        bf16x8 bfr[2][4];
        #pragma unroll
        for (int ks = 0; ks < 2; ++ks)
            #pragma unroll
            for (int sn = 0; sn < 4; ++sn) {
                int rb = 16 * sn + ln15;
                bfr[ks][sn] = *(const bf16x8*)&Bt[(rb * 8 + ((4 * ks + q) ^ (rb & 7))) * 8];
            }
        #pragma unroll
        for (int sm2 = 0; sm2 < 2; ++sm2) {
            int ra = 32 * w + 16 * sm2 + ln15;
            #pragma unroll
            for (int ks = 0; ks < 2; ++ks) {
                bf16x8 af = *(const bf16x8*)&At[(ra * 8 + ((4 * ks + q) ^ (ra & 7))) * 8];
                #pragma unroll
                for (int sn = 0; sn < 4; ++sn)
                    acc[sm2][sn] = __builtin_amdgcn_mfma_f32_16x16x32_bf16(
                        af, bfr[ks][sn], acc[sm2][sn], 0, 0, 0);
            }
        }
    }
    #pragma unroll
    for (int sm2 = 0; sm2 < 2; ++sm2)
        #pragma unroll
        for (int sn = 0; sn < 4; ++sn) {
            int col = n0 + 16 * sn + ln15;
            float bias = bo[col];
            #pragma unroll
            for (int r = 0; r < 4; ++r) {
                int row = m0 + 32 * w + 16 * sm2 + 4 * q + r;
                out[(size_t)row * 1024 + col] = acc[sm2][sn][r] + bias;
            }
        }
}

// ---------------------------------------------------------------------------
extern "C" void kernel_launch(void* const* d_in, const int* in_sizes, int n_in,
                              void* d_out, int out_size, void* d_ws, size_t ws_size,
                              hipStream_t stream)
{
    const float* x    = (const float*)d_in[0];
    const float* pos  = (const float*)d_in[1];
    const float* Wq   = (const float*)d_in[2];
    const float* bq   = (const float*)d_in[3];
    const float* Wkv  = (const float*)d_in[4];
    const float* bkv  = (const float*)d_in[5];
    const float* Wp   = (const float*)d_in[6];
    const float* bp   = (const float*)d_in[7];
    const float* Wo   = (const float*)d_in[8];
    const float* bo   = (const float*)d_in[9];
    float* out = (float*)d_out;

    const int M = 2 * SEQ_N;   // 4096
    char* ws = (char*)d_ws;
    bf16* xb     = (bf16*)ws;  ws += (size_t)M * DIM * 2;          //  8 MB
    bf16* posb   = (bf16*)ws;  ws += (size_t)SEQ_N * DIM * 2;      //  4 MB
    bf16* WqkvT  = (bf16*)ws;  ws += (size_t)3072 * 1024 * 2;      //  6 MB
    bf16* WoT    = (bf16*)ws;  ws += (size_t)DIM * DIM * 2;        //  2 MB
    bf16* WpT    = (bf16*)ws;  ws += (size_t)DH * DIM * 2;
    bf16* qbuf   = (bf16*)ws;  ws += (size_t)M * DIM * 2;
    bf16* kbuf   = (bf16*)ws;  ws += (size_t)M * DIM * 2;
    bf16* vtbuf  = (bf16*)ws;  ws += (size_t)M * DIM * 2;
    bf16* pfrag  = (bf16*)ws;  ws += (size_t)512 * 1024;
    bf16* abuf   = (bf16*)ws;

    // attn partials alias xb/posb/WqkvT (dead after qkvp):
    // Opart 1024*64*64*4 = 16 MB, MLpart 1024*64*8 = 0.5 MB  (< 18 MB region)
    float*  Opart  = (float*)d_ws;
    float2* MLpart = (float2*)((char*)d_ws + (size_t)1024 * 4096 * 4);

    dim3 blk(256);
    prep_kernel<<<dim3(10304), blk, 0, stream>>>(
        x, pos, Wq, Wkv, Wo, Wp, xb, posb, WqkvT, WoT, WpT);

    qkvp_kernel<<<dim3(25, 32), blk, 0, stream>>>(
        xb, WqkvT, posb, WpT, bq, bkv, bp, qbuf, kbuf, vtbuf, pfrag);

    attn_mfma_kernel<<<dim3(1536), blk, 0, stream>>>(
        qbuf, kbuf, vtbuf, pfrag, abuf, Opart, MLpart);

    merge_kernel<<<dim3(512), blk, 0, stream>>>(Opart, MLpart, abuf);

    outproj_kernel<<<dim3(16, 32), blk, 0, stream>>>(
        abuf, WoT, bo, out);
}

// Round 11
// 243.343 us; speedup vs baseline: 1.0609x; 1.0609x over previous
//
#include <hip/hip_runtime.h>
#include <hip/hip_bf16.h>
#include <cstdint>
#include <cstddef>

#define SEQ_N 2048
#define DIM   1024
#define NHEAD 16
#define DH    64

typedef __bf16 bf16;
typedef __attribute__((ext_vector_type(8))) __bf16 bf16x8;
typedef __attribute__((ext_vector_type(4))) __bf16 bf16x4;
typedef __attribute__((ext_vector_type(4))) float f32x4;

// async global->LDS 16B copy: LDS dest = wave-uniform base + lane*16
__device__ __forceinline__ void gl_lds16(const bf16* g, bf16* l) {
    __builtin_amdgcn_global_load_lds(
        (const __attribute__((address_space(1))) unsigned int*)g,
        (__attribute__((address_space(3))) unsigned int*)l, 16, 0, 0);
}

// ---------------------------------------------------------------------------
// prep: fused input cast (x, pos -> bf16, VECTORIZED stores) + transposes.
// ---------------------------------------------------------------------------
__global__ __launch_bounds__(256) void prep_kernel(
    const float* __restrict__ x, const float* __restrict__ pos,
    const float* __restrict__ Wq, const float* __restrict__ Wkv,
    const float* __restrict__ Wo, const float* __restrict__ Wp,
    bf16* __restrict__ xb, bf16* __restrict__ posb,
    bf16* __restrict__ WqkvT, bf16* __restrict__ WoT, bf16* __restrict__ WpT)
{
    int bid = blockIdx.x;
    if (bid < 6144) {
        const int NX = 4096 * 1024;
        int i = (bid * 256 + threadIdx.x) * 4;
        if (i < NX) {
            float4 v = *(const float4*)&x[i];
            bf16x4 o;
            o[0] = (bf16)v.x; o[1] = (bf16)v.y; o[2] = (bf16)v.z; o[3] = (bf16)v.w;
            *(bf16x4*)&xb[i] = o;
        } else {
            int j = i - NX;
            float4 v = *(const float4*)&pos[j];
            bf16x4 o;
            o[0] = (bf16)v.x; o[1] = (bf16)v.y; o[2] = (bf16)v.z; o[3] = (bf16)v.w;
            *(bf16x4*)&posb[j] = o;
        }
        return;
    }
    __shared__ float t[32][33];
    bid -= 6144;
    const float* src; bf16* dst; int tidx, nx, N;
    if (bid < 1024)      { src = Wq;  dst = WqkvT;                       tidx = bid;        nx = 32; N = 1024; }
    else if (bid < 3072) { src = Wkv; dst = WqkvT + (size_t)1024 * 1024; tidx = bid - 1024; nx = 64; N = 2048; }
    else if (bid < 4096) { src = Wo;  dst = WoT;                         tidx = bid - 3072; nx = 32; N = 1024; }
    else                 { src = Wp;  dst = WpT;                         tidx = bid - 4096; nx = 2;  N = 64;   }
    int n0 = (tidx % nx) * 32, k0 = (tidx / nx) * 32;
    int tx = threadIdx.x & 31, ty = threadIdx.x >> 5;
    #pragma unroll
    for (int r = ty; r < 32; r += 8)
        t[r][tx] = src[(size_t)(k0 + r) * N + n0 + tx];
    __syncthreads();
    #pragma unroll
    for (int r = ty; r < 32; r += 8)
        dst[(size_t)(n0 + r) * 1024 + k0 + tx] = (bf16)t[tx][r];
}

// ---------------------------------------------------------------------------
// qkv projection + p projection, one dispatch. grid (25, 32).
// q output PRE-SCALED by 0.125*log2(e): folds attn scale + exp->exp2 (exact).
// XCD-aware bijective remap: f = bx+25*by (HW linear id); xcd=f&7, j=f>>3;
// by'=4*xcd+j/25, bx'=j%25 -> each XCD owns 4 contiguous by-panels (1 MB xb
// L2-resident; WqkvT panels reused 4x from L2). Halves qkvp HBM traffic.
// ---------------------------------------------------------------------------
__global__ __launch_bounds__(256) void qkvp_kernel(
    const bf16* __restrict__ xb, const bf16* __restrict__ WqkvT,
    const bf16* __restrict__ posb, const bf16* __restrict__ WpT,
    const float* __restrict__ bq, const float* __restrict__ bkv,
    const float* __restrict__ bp,
    bf16* __restrict__ qbuf, bf16* __restrict__ kbuf,
    bf16* __restrict__ vtbuf, bf16* __restrict__ pfrag)
{
    __shared__ __align__(16) bf16 sm[128 * 132];   // At|Bt staging / V bounce
    bf16* At = sm;
    bf16* Bt = sm + 128 * 64;
    const int tid = threadIdx.x, w = tid >> 6, lane = tid & 63;
    const int q = lane >> 4, ln15 = lane & 15;
    const int lr = lane >> 3, c_log = (lane & 7) ^ lr;
    const int f  = (int)blockIdx.x + 25 * (int)blockIdx.y;
    const int jx = f >> 3;
    const int bx = jx % 25;
    const int by = ((f & 7) << 2) + jx / 25;
    const int m0 = by * 128;

    if (bx == 24) {
        if (by >= 16) return;
        f32x4 acc[2][4] = {};
        for (int k0 = 0; k0 < 1024; k0 += 64) {
            __syncthreads();
            #pragma unroll
            for (int t = 0; t < 4; ++t)
                gl_lds16(&posb[(size_t)(m0 + 32 * w + 8 * t + lr) * 1024 + k0 + c_log * 8],
                         &At[(32 * w + 8 * t) * 64]);
            #pragma unroll
            for (int t = 0; t < 2; ++t)
                gl_lds16(&WpT[(size_t)(16 * w + 8 * t + lr) * 1024 + k0 + c_log * 8],
                         &Bt[(16 * w + 8 * t) * 64]);
            __syncthreads();
            bf16x8 bfr[2][4];
            #pragma unroll
            for (int ks = 0; ks < 2; ++ks)
                #pragma unroll
                for (int sn = 0; sn < 4; ++sn) {
                    int rb = 16 * sn + ln15;
                    bfr[ks][sn] = *(const bf16x8*)&Bt[(rb * 8 + ((4 * ks + q) ^ (rb & 7))) * 8];
                }
            #pragma unroll
            for (int sm2 = 0; sm2 < 2; ++sm2) {
                int ra = 32 * w + 16 * sm2 + ln15;
                #pragma unroll
                for (int ks = 0; ks < 2; ++ks) {
                    bf16x8 af = *(const bf16x8*)&At[(ra * 8 + ((4 * ks + q) ^ (ra & 7))) * 8];
                    #pragma unroll
                    for (int sn = 0; sn < 4; ++sn)
                        acc[sm2][sn] = __builtin_amdgcn_mfma_f32_16x16x32_bf16(
                            af, bfr[ks][sn], acc[sm2][sn], 0, 0, 0);
                }
            }
        }
        #pragma unroll
        for (int sm2 = 0; sm2 < 2; ++sm2)
            #pragma unroll
            for (int sn = 0; sn < 4; ++sn)
                #pragma unroll
                for (int r = 0; r < 4; ++r) {
                    int row = m0 + 32 * w + 16 * sm2 + 4 * q + r;
                    int d = 16 * sn + ln15;
                    int sb = row >> 4, lnp = row & 15;
                    int ks2 = d >> 5, qd = (d >> 3) & 3, e = d & 7;
                    pfrag[(((size_t)sb * 2 + ks2) * 64 + qd * 16 + lnp) * 8 + e] =
                        (bf16)(acc[sm2][sn][r] + bp[d]);
                }
        return;
    }

    // ---- qkv GEMM tile ----
    const int n0 = bx * 128;
    const int wm = w >> 1, wn = w & 1;
    f32x4 acc[4][4] = {};

    for (int k0 = 0; k0 < 1024; k0 += 64) {
        __syncthreads();
        #pragma unroll
        for (int t = 0; t < 4; ++t) {
            int r = 32 * w + 8 * t + lr;
            gl_lds16(&xb[(size_t)(m0 + r) * 1024 + k0 + c_log * 8],
                     &At[(32 * w + 8 * t) * 64]);
            gl_lds16(&WqkvT[(size_t)(n0 + r) * 1024 + k0 + c_log * 8],
                     &Bt[(32 * w + 8 * t) * 64]);
        }
        __syncthreads();

        bf16x8 af[2][4], bfr[2][4];
        #pragma unroll
        for (int ks = 0; ks < 2; ++ks)
            #pragma unroll
            for (int s = 0; s < 4; ++s) {
                int ra = 64 * wm + 16 * s + ln15;
                af[ks][s]  = *(const bf16x8*)&At[(ra * 8 + ((4 * ks + q) ^ (ra & 7))) * 8];
                int rb = 64 * wn + 16 * s + ln15;
                bfr[ks][s] = *(const bf16x8*)&Bt[(rb * 8 + ((4 * ks + q) ^ (rb & 7))) * 8];
            }
        #pragma unroll
        for (int ks = 0; ks < 2; ++ks)
            #pragma unroll
            for (int si = 0; si < 4; ++si)
                #pragma unroll
                for (int sj = 0; sj < 4; ++sj)
                    acc[si][sj] = __builtin_amdgcn_mfma_f32_16x16x32_bf16(
                        af[ks][si], bfr[ks][sj], acc[si][sj], 0, 0, 0);
    }

    if (bx < 16) {
        // q (pre-scaled) / k natural layout
        const float QSCL = 0.125f * 1.44269504088896341f;
        #pragma unroll
        for (int si = 0; si < 4; ++si)
            #pragma unroll
            for (int sj = 0; sj < 4; ++sj)
                #pragma unroll
                for (int r = 0; r < 4; ++r) {
                    int row = m0 + 64 * wm + 16 * si + 4 * q + r;
                    int col = n0 + 64 * wn + 16 * sj + ln15;
                    float v = acc[si][sj][r] + (col < 1024 ? bq[col] : bkv[col - 1024]);
                    if (col < 1024) qbuf[(size_t)row * 1024 + col] = (bf16)(v * QSCL);
                    else            kbuf[(size_t)row * 1024 + (col - 1024)] = (bf16)v;
                }
    } else {
        // V: transpose to (b,h,d,t) via LDS bounce, 16B coalesced stores
        __syncthreads();   // all waves done reading At/Bt
        #pragma unroll
        for (int si = 0; si < 4; ++si)
            #pragma unroll
            for (int sj = 0; sj < 4; ++sj) {
                int dL = 64 * wn + 16 * sj + ln15;        // 0..127
                int tL = 64 * wm + 16 * si + 4 * q;       // +r
                float bias = bkv[1024 + (bx - 16) * 128 + dL];
                bf16x4 o4;
                #pragma unroll
                for (int r = 0; r < 4; ++r)
                    o4[r] = (bf16)(acc[si][sj][r] + bias);
                *(bf16x4*)&sm[dL * 132 + tL] = o4;
            }
        __syncthreads();
        const int b = m0 >> 11;
        const int t0 = m0 & 2047;
        const int h0 = (bx - 16) * 2;
        #pragma unroll
        for (int p = 0; p < 16; ++p) {
            int d = (tid >> 5) + 8 * p;
            int t = (tid & 31) * 4;
            bf16x4 v4 = *(const bf16x4*)&sm[d * 132 + t];
            int rowv = (b * NHEAD + h0 + (d >> 6)) * DH + (d & 63);
            *(bf16x4*)&vtbuf[(size_t)rowv * SEQ_N + t0 + t] = v4;
        }
    }
}

// ---------------------------------------------------------------------------
// MFMA flash attention — EXACT R6 restore (measured best: 85.7 us attn,
// 244.9 us total). KV-split decomposition, 1536 blocks, 4 resident/CU
// (35,328 B LDS) + hardware backfill. Decode: s ascending == length
// descending, per-XCD bh locality, bijective over (bh, qblk, part).
// Inner loop: gl_lds K+V, inline pfA S2 ring, 2 barriers, pre-scaled q /
// exp2 softmax, bias as MFMA C-init, alpha==1 skip, direct-global Q.
// R7-R10 lessons: no launch-bounds squeeze (spills), no Pw/S2L alias gain,
// no KVBLK=128 (occupancy + bank conflicts), DS vectorization neutral.
// ---------------------------------------------------------------------------
__global__ __launch_bounds__(256, 4) void attn_mfma_kernel(
    const bf16* __restrict__ qb,    // [4096][1024], pre-scaled
    const bf16* __restrict__ kb,    // [4096][1024]
    const bf16* __restrict__ vt,    // [(b,h,d)][2048]
    const bf16* __restrict__ pfrag, // fragment-ready p
    bf16* __restrict__ ob,          // [4096][1024]
    float* __restrict__ Opart,      // [1024][64][64] fp32 partials
    float2* __restrict__ MLpart)    // [1024][64] (m,l)
{
    // ---- block decode: f -> (bh, qblk, [lo,hi), part) ----
    const int f   = (int)blockIdx.x;   // 0..1535
    const int xcd = f & 7;
    const int jj  = f >> 3;            // 0..191
    const int s   = jj >> 2;           // 0..47, ascending == length descending
    const int bh  = xcd * 4 + (jj & 3);
    int qblk, lo, hi, part;            // part: -1 single, 0/1 split halves
    if (s < 16) { qblk = 16 + s; lo = 0; hi = 16; part = 0; }
    else {
        int k = (s - 16) >> 1;
        if (((s - 16) & 1) == 0) { qblk = 31 - k; lo = 16; hi = qblk + 1; part = 1; }
        else                     { qblk = 15 - k; lo = 0;  hi = qblk + 1; part = -1; }
    }
    const int bi = bh >> 4, hh = bh & 15;
    const int i0 = qblk << 6;
    const int tid = threadIdx.x, w = tid >> 6, lane = tid & 63;
    const int q = lane >> 4, ln15 = lane & 15;
    const int lr = lane >> 3, c_log = (lane & 7) ^ lr;

    __shared__ __align__(16) bf16 smem[17664];
    bf16* S2L = smem + w * 1344;           // per-wave 16 x 84   [0,5376)
    bf16* Ks  = smem + 5376;               // 64x64 swizzled
    bf16* Vs  = smem + 9472;               // 64x64 swizzled
    bf16* Pw  = smem + 13568 + w * 1024;   // per-wave 16 x 64

    const bf16* qbase = qb + ((size_t)(bi * SEQ_N + i0)) * DIM + hh * DH;
    const bf16* kbase = kb + ((size_t)bi * SEQ_N) * DIM + hh * DH;
    const bf16* vbase = vt + ((size_t)(bi * NHEAD + hh) * DH) * SEQ_N;

    // ---- prologue: Q fragments direct from global (pre-scaled) ----
    bf16x8 qf0 = *(const bf16x8*)&qbase[(size_t)(16 * w + ln15) * DIM + q * 8];
    bf16x8 qf1 = *(const bf16x8*)&qbase[(size_t)(16 * w + ln15) * DIM + 32 + q * 8];

    const int A0 = 127 - 4 * qblk - w;
    f32x4 s2r4;
    {
        int sb0 = A0 + 4 * lo;
        bf16x8 f0 = *(const bf16x8*)&pfrag[(((size_t)sb0 * 2 + 0) * 64 + lane) * 8];
        bf16x8 f1 = *(const bf16x8*)&pfrag[(((size_t)sb0 * 2 + 1) * 64 + lane) * 8];
        f32x4 a = {0.f, 0.f, 0.f, 0.f};
        a = __builtin_amdgcn_mfma_f32_16x16x32_bf16(f0, qf0, a, 0, 0, 0);
        a = __builtin_amdgcn_mfma_f32_16x16x32_bf16(f1, qf1, a, 0, 0, 0);
        s2r4 = a;
    }

    float m_run = -1e30f, l_run = 0.f;
    f32x4 O_T[4] = {};

    for (int jt = lo; jt < hi; ++jt) {
        const int j0 = jt << 6;

        // [1] pfA for S2(jt) (short live range; no spill at 60 VGPR)
        bf16x8 pfA[4][2];
        #pragma unroll
        for (int ss = 1; ss <= 4; ++ss) {
            int sb = A0 + 4 * jt + ss;
            if (sb > 127) sb = 127;
            pfA[ss-1][0] = *(const bf16x8*)&pfrag[(((size_t)sb * 2 + 0) * 64 + lane) * 8];
            pfA[ss-1][1] = *(const bf16x8*)&pfrag[(((size_t)sb * 2 + 1) * 64 + lane) * 8];
        }
        // [2] stage K/V tile jt (async DMA; drained by the barrier below)
        #pragma unroll
        for (int t = 0; t < 2; ++t) {
            int r = 16 * w + 8 * t + lr;
            gl_lds16(kbase + (size_t)(j0 + r) * DIM + c_log * 8,
                     &Ks[(16 * w + 8 * t) * 64]);
            gl_lds16(vbase + (size_t)r * SEQ_N + j0 + c_log * 8,
                     &Vs[(16 * w + 8 * t) * 64]);
        }

        // [3] S2(jt): rel-pos bias ring (covers the gl_lds latency)
        {
            f32x4 s2r[5];
            s2r[0] = s2r4;
            #pragma unroll
            for (int ss = 1; ss <= 4; ++ss) {
                f32x4 a = {0.f, 0.f, 0.f, 0.f};
                a = __builtin_amdgcn_mfma_f32_16x16x32_bf16(pfA[ss-1][0], qf0, a, 0, 0, 0);
                a = __builtin_amdgcn_mfma_f32_16x16x32_bf16(pfA[ss-1][1], qf1, a, 0, 0, 0);
                s2r[ss] = a;
            }
            s2r4 = s2r[4];
            #pragma unroll
            for (int ss = 0; ss < 5; ++ss)
                #pragma unroll
                for (int r = 0; r < 4; ++r)
                    S2L[ln15 * 84 + 16 * ss + 4 * q + r] = (bf16)s2r[ss][r];
        }

        __syncthreads();

        // [4] QK^T, bias as C-init (already exp2-domain via pre-scaled q)
        float sv[4][4];
        __builtin_amdgcn_s_setprio(1);
        #pragma unroll
        for (int sn = 0; sn < 4; ++sn) {
            int rk = 16 * sn + ln15;
            bf16x8 k0f = *(const bf16x8*)&Ks[(rk * 8 + ((q    ) ^ (rk & 7))) * 8];
            bf16x8 k1f = *(const bf16x8*)&Ks[(rk * 8 + ((4 + q) ^ (rk & 7))) * 8];
            f32x4 a;
            #pragma unroll
            for (int r = 0; r < 4; ++r)
                a[r] = (float)S2L[ln15 * 84 + 15 - ln15 + 16 * sn + 4 * q + r];
            a = __builtin_amdgcn_mfma_f32_16x16x32_bf16(k0f, qf0, a, 0, 0, 0);
            a = __builtin_amdgcn_mfma_f32_16x16x32_bf16(k1f, qf1, a, 0, 0, 0);
            #pragma unroll
            for (int r = 0; r < 4; ++r)
                sv[sn][r] = a[r];
        }
        __builtin_amdgcn_s_setprio(0);
        if (jt == qblk) {
            #pragma unroll
            for (int sn = 0; sn < 4; ++sn)
                #pragma unroll
                for (int r = 0; r < 4; ++r)
                    if (16 * sn + 4 * q + r > 16 * w + ln15)
                        sv[sn][r] = -1e30f;
        }

        // [5] online softmax (exp2 domain)
        float mx = sv[0][0];
        #pragma unroll
        for (int sn = 0; sn < 4; ++sn)
            #pragma unroll
            for (int r = 0; r < 4; ++r)
                mx = fmaxf(mx, sv[sn][r]);
        mx = fmaxf(mx, __shfl_xor(mx, 16));
        mx = fmaxf(mx, __shfl_xor(mx, 32));
        const float mn = fmaxf(m_run, mx);
        float sum = 0.f;
        #pragma unroll
        for (int sn = 0; sn < 4; ++sn)
            #pragma unroll
            for (int r = 0; r < 4; ++r) {
                float e = exp2f(sv[sn][r] - mn);
                sv[sn][r] = e;
                sum += e;
            }
        sum += __shfl_xor(sum, 16);
        sum += __shfl_xor(sum, 32);
        if (__all(mx <= m_run)) {
            l_run += sum;                       // alpha == 1 exactly
        } else {
            const float alpha = exp2f(m_run - mn);
            l_run = l_run * alpha + sum;
            #pragma unroll
            for (int sd = 0; sd < 4; ++sd)
                #pragma unroll
                for (int r = 0; r < 4; ++r)
                    O_T[sd][r] *= alpha;
        }
        m_run = mn;

        // [6] P -> Pw (per-wave LDS shuffle for the PV B-operand)
        #pragma unroll
        for (int sn = 0; sn < 4; ++sn)
            #pragma unroll
            for (int r = 0; r < 4; ++r) {
                int chunk = (2 * sn + (q >> 1)) ^ (ln15 & 7);
                Pw[ln15 * 64 + chunk * 8 + 4 * (q & 1) + r] = (bf16)sv[sn][r];
            }

        __builtin_amdgcn_s_waitcnt(0);

        // [7] PV from Vs (LDS) and Pw
        __builtin_amdgcn_s_setprio(1);
        #pragma unroll
        for (int ks = 0; ks < 2; ++ks) {
            bf16x8 pT = *(const bf16x8*)&Pw[ln15 * 64 + (((4 * ks + q) ^ (ln15 & 7))) * 8];
            #pragma unroll
            for (int sd = 0; sd < 4; ++sd) {
                int rv = 16 * sd + ln15;
                bf16x8 vf = *(const bf16x8*)&Vs[(rv * 8 + ((4 * ks + q) ^ (rv & 7))) * 8];
                O_T[sd] = __builtin_amdgcn_mfma_f32_16x16x32_bf16(vf, pT, O_T[sd], 0, 0, 0);
            }
        }
        __builtin_amdgcn_s_setprio(0);
        __syncthreads();
    }

    const int row = 16 * w + ln15;
    if (part < 0) {
        // complete block: normalize and write bf16 output
        const float inv = 1.0f / l_run;
        const size_t grow = (size_t)bi * SEQ_N + i0 + row;
        #pragma unroll
        for (int sd = 0; sd < 4; ++sd) {
            bf16x4 o4;
            #pragma unroll
            for (int r = 0; r < 4; ++r)
                o4[r] = (bf16)(O_T[sd][r] * inv);
            *(bf16x4*)&ob[grow * DIM + hh * DH + 16 * sd + 4 * q] = o4;
        }
    } else {
        // split part: write un-normalized fp32 O + (m,l) for the merge
        const int slot = (bh * 16 + (qblk - 16)) * 2 + part;
        float* op = Opart + (size_t)slot * 4096 + row * 64;
        #pragma unroll
        for (int sd = 0; sd < 4; ++sd)
            *(f32x4*)&op[16 * sd + 4 * q] = O_T[sd];
        if (lane < 16)
            MLpart[slot * 64 + row] = make_float2(m_run, l_run);
    }
}

// ---------------------------------------------------------------------------
// merge: combine the two KV-half partials of each qblk>=16 row-block.
// Exact online-softmax merge (exp2 domain). 512 blocks x 256 threads.
// ---------------------------------------------------------------------------
__global__ __launch_bounds__(256) void merge_kernel(
    const float* __restrict__ Opart, const float2* __restrict__ MLpart,
    bf16* __restrict__ ob)
{
    const int pb = blockIdx.x;             // 0..511
    const int bh = pb >> 4, qblk = 16 + (pb & 15);
    const int bi = bh >> 4, hh = bh & 15;
    const int row = threadIdx.x >> 2;
    const int d0 = (threadIdx.x & 3) * 16;

    float2 ml0 = MLpart[(pb * 2 + 0) * 64 + row];
    float2 ml1 = MLpart[(pb * 2 + 1) * 64 + row];
    float m = fmaxf(ml0.x, ml1.x);
    float a0 = exp2f(ml0.x - m), a1 = exp2f(ml1.x - m);
    float inv = 1.0f / (ml0.y * a0 + ml1.y * a1);

    const float* o0 = Opart + ((size_t)(pb * 2 + 0)) * 4096 + row * 64 + d0;
    const float* o1 = Opart + ((size_t)(pb * 2 + 1)) * 4096 + row * 64 + d0;
    bf16* dst = ob + ((size_t)(bi * SEQ_N + qblk * 64 + row)) * DIM + hh * DH + d0;
    #pragma unroll
    for (int k = 0; k < 4; ++k) {
        float4 v0 = *(const float4*)&o0[4 * k];
        float4 v1 = *(const float4*)&o1[4 * k];
        bf16x4 o4;
        o4[0] = (bf16)((v0.x * a0 + v1.x * a1) * inv);
        o4[1] = (bf16)((v0.y * a0 + v1.y * a1) * inv);
        o4[2] = (bf16)((v0.z * a0 + v1.z * a1) * inv);
        o4[3] = (bf16)((v0.w * a0 + v1.w * a1) * inv);
        *(bf16x4*)&dst[4 * k] = o4;
    }
}

// ---------------------------------------------------------------------------
// out = abuf @ WoT^T + bo, fp32 out. 128x64 tiles -> grid (16,32), 2/CU.
// ---------------------------------------------------------------------------
__global__ __launch_bounds__(256) void outproj_kernel(
    const bf16* __restrict__ ab, const bf16* __restrict__ WoT,
    const float* __restrict__ bo, float* __restrict__ out)
{
    __shared__ __align__(16) bf16 At[128 * 64];
    __shared__ __align__(16) bf16 Bt[64 * 64];
    const int tid = threadIdx.x, w = tid >> 6, lane = tid & 63;
    const int q = lane >> 4, ln15 = lane & 15;
    const int lr = lane >> 3, c_log = (lane & 7) ^ lr;
    const int m0 = blockIdx.y * 128, n0 = blockIdx.x * 64;

    f32x4 acc[2][4] = {};
    for (int k0 = 0; k0 < 1024; k0 += 64) {
        __syncthreads();
        #pragma unroll
        for (int t = 0; t < 4; ++t)
            gl_lds16(&ab[(size_t)(m0 + 32 * w + 8 * t + lr) * 1024 + k0 + c_log * 8],
                     &At[(32 * w + 8 * t) * 64]);
        #pragma unroll
        for (int t = 0; t < 2; ++t)
            gl_lds16(&WoT[(size_t)(n0 + 16 * w + 8 * t + lr) * 1024 + k0 + c_log * 8],
                     &Bt[(16 * w + 8 * t) * 64]);
        __syncthreads();

        bf16x8 bfr[2][4];
        #pragma unroll
        for (int ks = 0; ks < 2; ++ks)
            #pragma unroll
            for (int sn = 0; sn < 4; ++sn) {
                int rb = 16 * sn + ln15;
                bfr[ks][sn] = *(const bf16x8*)&Bt[(rb * 8 + ((4 * ks + q) ^ (rb & 7))) * 8];
            }
        #pragma unroll
        for (int sm2 = 0; sm2 < 2; ++sm2) {
            int ra = 32 * w + 16 * sm2 + ln15;
            #pragma unroll
            for (int ks = 0; ks < 2; ++ks) {
                bf16x8 af = *(const bf16x8*)&At[(ra * 8 + ((4 * ks + q) ^ (ra & 7))) * 8];
                #pragma unroll
                for (int sn = 0; sn < 4; ++sn)
                    acc[sm2][sn] = __builtin_amdgcn_mfma_f32_16x16x32_bf16(
                        af, bfr[ks][sn], acc[sm2][sn], 0, 0, 0);
            }
        }
    }
    #pragma unroll
    for (int sm2 = 0; sm2 < 2; ++sm2)
        #pragma unroll
        for (int sn = 0; sn < 4; ++sn) {
            int col = n0 + 16 * sn + ln15;
            float bias = bo[col];
            #pragma unroll
            for (int r = 0; r < 4; ++r) {
                int row = m0 + 32 * w + 16 * sm2 + 4 * q + r;
                out[(size_t)row * 1024 + col] = acc[sm2][sn][r] + bias;
            }
        }
}

// ---------------------------------------------------------------------------
extern "C" void kernel_launch(void* const* d_in, const int* in_sizes, int n_in,
                              void* d_out, int out_size, void* d_ws, size_t ws_size,
                              hipStream_t stream)
{
    const float* x    = (const float*)d_in[0];
    const float* pos  = (const float*)d_in[1];
    const float* Wq   = (const float*)d_in[2];
    const float* bq   = (const float*)d_in[3];
    const float* Wkv  = (const float*)d_in[4];
    const float* bkv  = (const float*)d_in[5];
    const float* Wp   = (const float*)d_in[6];
    const float* bp   = (const float*)d_in[7];
    const float* Wo   = (const float*)d_in[8];
    const float* bo   = (const float*)d_in[9];
    float* out = (float*)d_out;

    const int M = 2 * SEQ_N;   // 4096
    char* ws = (char*)d_ws;
    bf16* xb     = (bf16*)ws;  ws += (size_t)M * DIM * 2;          //  8 MB
    bf16* posb   = (bf16*)ws;  ws += (size_t)SEQ_N * DIM * 2;      //  4 MB
    bf16* WqkvT  = (bf16*)ws;  ws += (size_t)3072 * 1024 * 2;      //  6 MB
    bf16* WoT    = (bf16*)ws;  ws += (size_t)DIM * DIM * 2;        //  2 MB
    bf16* WpT    = (bf16*)ws;  ws += (size_t)DH * DIM * 2;
    bf16* qbuf   = (bf16*)ws;  ws += (size_t)M * DIM * 2;
    bf16* kbuf   = (bf16*)ws;  ws += (size_t)M * DIM * 2;
    bf16* vtbuf  = (bf16*)ws;  ws += (size_t)M * DIM * 2;
    bf16* pfrag  = (bf16*)ws;  ws += (size_t)512 * 1024;
    bf16* abuf   = (bf16*)ws;

    // attn partials alias xb/posb/WqkvT (dead after qkvp):
    // Opart 1024*64*64*4 = 16 MB, MLpart 1024*64*8 = 0.5 MB  (< 18 MB region)
    float*  Opart  = (float*)d_ws;
    float2* MLpart = (float2*)((char*)d_ws + (size_t)1024 * 4096 * 4);

    dim3 blk(256);
    prep_kernel<<<dim3(10304), blk, 0, stream>>>(
        x, pos, Wq, Wkv, Wo, Wp, xb, posb, WqkvT, WoT, WpT);

    qkvp_kernel<<<dim3(25, 32), blk, 0, stream>>>(
        xb, WqkvT, posb, WpT, bq, bkv, bp, qbuf, kbuf, vtbuf, pfrag);

    attn_mfma_kernel<<<dim3(1536), blk, 0, stream>>>(
        qbuf, kbuf, vtbuf, pfrag, abuf, Opart, MLpart);

    merge_kernel<<<dim3(512), blk, 0, stream>>>(Opart, MLpart, abuf);

    outproj_kernel<<<dim3(16, 32), blk, 0, stream>>>(
        abuf, WoT, bo, out);
}

// Round 12
// 230.703 us; speedup vs baseline: 1.1190x; 1.0548x over previous
//
#include <hip/hip_runtime.h>
#include <hip/hip_bf16.h>
#include <cstdint>
#include <cstddef>

#define SEQ_N 2048
#define DIM   1024
#define NHEAD 16
#define DH    64

typedef __bf16 bf16;
typedef __attribute__((ext_vector_type(8))) __bf16 bf16x8;
typedef __attribute__((ext_vector_type(4))) __bf16 bf16x4;
typedef __attribute__((ext_vector_type(4))) float f32x4;

// async global->LDS 16B copy: LDS dest = wave-uniform base + lane*16
__device__ __forceinline__ void gl_lds16(const bf16* g, bf16* l) {
    __builtin_amdgcn_global_load_lds(
        (const __attribute__((address_space(1))) unsigned int*)g,
        (__attribute__((address_space(3))) unsigned int*)l, 16, 0, 0);
}

// ---------------------------------------------------------------------------
// prep: fused input cast (x, pos -> bf16) + weight transposes.
// Both cast AND transpose stores vectorized (bf16x4, 8B).
// ---------------------------------------------------------------------------
__global__ __launch_bounds__(256) void prep_kernel(
    const float* __restrict__ x, const float* __restrict__ pos,
    const float* __restrict__ Wq, const float* __restrict__ Wkv,
    const float* __restrict__ Wo, const float* __restrict__ Wp,
    bf16* __restrict__ xb, bf16* __restrict__ posb,
    bf16* __restrict__ WqkvT, bf16* __restrict__ WoT, bf16* __restrict__ WpT)
{
    int bid = blockIdx.x;
    if (bid < 6144) {
        const int NX = 4096 * 1024;
        int i = (bid * 256 + threadIdx.x) * 4;
        if (i < NX) {
            float4 v = *(const float4*)&x[i];
            bf16x4 o;
            o[0] = (bf16)v.x; o[1] = (bf16)v.y; o[2] = (bf16)v.z; o[3] = (bf16)v.w;
            *(bf16x4*)&xb[i] = o;
        } else {
            int j = i - NX;
            float4 v = *(const float4*)&pos[j];
            bf16x4 o;
            o[0] = (bf16)v.x; o[1] = (bf16)v.y; o[2] = (bf16)v.z; o[3] = (bf16)v.w;
            *(bf16x4*)&posb[j] = o;
        }
        return;
    }
    __shared__ float t[32][33];
    bid -= 6144;
    const float* src; bf16* dst; int tidx, nx, N;
    if (bid < 1024)      { src = Wq;  dst = WqkvT;                       tidx = bid;        nx = 32; N = 1024; }
    else if (bid < 3072) { src = Wkv; dst = WqkvT + (size_t)1024 * 1024; tidx = bid - 1024; nx = 64; N = 2048; }
    else if (bid < 4096) { src = Wo;  dst = WoT;                         tidx = bid - 3072; nx = 32; N = 1024; }
    else                 { src = Wp;  dst = WpT;                         tidx = bid - 4096; nx = 2;  N = 64;   }
    int n0 = (tidx % nx) * 32, k0 = (tidx / nx) * 32;
    int tx = threadIdx.x & 31, ty = threadIdx.x >> 5;
    #pragma unroll
    for (int r = ty; r < 32; r += 8)
        t[r][tx] = src[(size_t)(k0 + r) * N + n0 + tx];
    __syncthreads();
    // vectorized transpose store: 8 threads x bf16x4 per row
    int rowi = threadIdx.x >> 3, colg = threadIdx.x & 7;
    bf16x4 o;
    #pragma unroll
    for (int e = 0; e < 4; ++e)
        o[e] = (bf16)t[colg * 4 + e][rowi];
    *(bf16x4*)&dst[(size_t)(n0 + rowi) * 1024 + k0 + colg * 4] = o;
}

// ---------------------------------------------------------------------------
// qkv projection + p projection. grid (25, 32), XCD-swizzled (R11).
// q output PRE-SCALED by 0.125*log2(e) (exact).
// T3 minimal 2-phase pipeline: double-buffered LDS (64 KB, 2 blocks/CU);
// per K-step: issue STAGE(next buf) -> compute(cur buf) -> one barrier
// (compiler vmcnt(0) drain lands AFTER ~260cy of compute, hiding staging
// latency -- was exposed before compute in the old 2-barrier loop).
// ---------------------------------------------------------------------------
__global__ __launch_bounds__(256) void qkvp_kernel(
    const bf16* __restrict__ xb, const bf16* __restrict__ WqkvT,
    const bf16* __restrict__ posb, const bf16* __restrict__ WpT,
    const float* __restrict__ bq, const float* __restrict__ bkv,
    const float* __restrict__ bp,
    bf16* __restrict__ qbuf, bf16* __restrict__ kbuf,
    bf16* __restrict__ vtbuf, bf16* __restrict__ pfrag)
{
    __shared__ __align__(16) bf16 sm[32768];   // 2 x (At 8192 | Bt 8192); V-bounce aliases
    const int tid = threadIdx.x, w = tid >> 6, lane = tid & 63;
    const int q = lane >> 4, ln15 = lane & 15;
    const int lr = lane >> 3, c_log = (lane & 7) ^ lr;
    const int f  = (int)blockIdx.x + 25 * (int)blockIdx.y;
    const int jx = f >> 3;
    const int bx = jx % 25;
    const int by = ((f & 7) << 2) + jx / 25;
    const int m0 = by * 128;

    if (bx == 24) {
        if (by >= 16) return;
        f32x4 acc[2][4] = {};
        // prologue: stage tile 0 into buf0
        #pragma unroll
        for (int t = 0; t < 4; ++t)
            gl_lds16(&posb[(size_t)(m0 + 32 * w + 8 * t + lr) * 1024 + c_log * 8],
                     &sm[(32 * w + 8 * t) * 64]);
        #pragma unroll
        for (int t = 0; t < 2; ++t)
            gl_lds16(&WpT[(size_t)(16 * w + 8 * t + lr) * 1024 + c_log * 8],
                     &sm[8192 + (16 * w + 8 * t) * 64]);
        __syncthreads();
        int cur = 0;
        for (int kt = 0; kt < 16; ++kt) {
            bf16* At = sm + cur * 16384;
            bf16* Bt = At + 8192;
            if (kt + 1 < 16) {
                bf16* Atn = sm + (cur ^ 1) * 16384;
                bf16* Btn = Atn + 8192;
                int k0 = (kt + 1) * 64;
                #pragma unroll
                for (int t = 0; t < 4; ++t)
                    gl_lds16(&posb[(size_t)(m0 + 32 * w + 8 * t + lr) * 1024 + k0 + c_log * 8],
                             &Atn[(32 * w + 8 * t) * 64]);
                #pragma unroll
                for (int t = 0; t < 2; ++t)
                    gl_lds16(&WpT[(size_t)(16 * w + 8 * t + lr) * 1024 + k0 + c_log * 8],
                             &Btn[(16 * w + 8 * t) * 64]);
            }
            bf16x8 bfr[2][4];
            #pragma unroll
            for (int ks = 0; ks < 2; ++ks)
                #pragma unroll
                for (int sn = 0; sn < 4; ++sn) {
                    int rb = 16 * sn + ln15;
                    bfr[ks][sn] = *(const bf16x8*)&Bt[(rb * 8 + ((4 * ks + q) ^ (rb & 7))) * 8];
                }
            #pragma unroll
            for (int sm2 = 0; sm2 < 2; ++sm2) {
                int ra = 32 * w + 16 * sm2 + ln15;
                #pragma unroll
                for (int ks = 0; ks < 2; ++ks) {
                    bf16x8 af = *(const bf16x8*)&At[(ra * 8 + ((4 * ks + q) ^ (ra & 7))) * 8];
                    #pragma unroll
                    for (int sn = 0; sn < 4; ++sn)
                        acc[sm2][sn] = __builtin_amdgcn_mfma_f32_16x16x32_bf16(
                            af, bfr[ks][sn], acc[sm2][sn], 0, 0, 0);
                }
            }
            __syncthreads();
            cur ^= 1;
        }
        #pragma unroll
        for (int sm2 = 0; sm2 < 2; ++sm2)
            #pragma unroll
            for (int sn = 0; sn < 4; ++sn)
                #pragma unroll
                for (int r = 0; r < 4; ++r) {
                    int row = m0 + 32 * w + 16 * sm2 + 4 * q + r;
                    int d = 16 * sn + ln15;
                    int sb = row >> 4, lnp = row & 15;
                    int ks2 = d >> 5, qd = (d >> 3) & 3, e = d & 7;
                    pfrag[(((size_t)sb * 2 + ks2) * 64 + qd * 16 + lnp) * 8 + e] =
                        (bf16)(acc[sm2][sn][r] + bp[d]);
                }
        return;
    }

    // ---- qkv GEMM tile ----
    const int n0 = bx * 128;
    const int wm = w >> 1, wn = w & 1;
    f32x4 acc[4][4] = {};

    // prologue: stage tile 0 into buf0
    #pragma unroll
    for (int t = 0; t < 4; ++t) {
        int r = 32 * w + 8 * t + lr;
        gl_lds16(&xb[(size_t)(m0 + r) * 1024 + c_log * 8],
                 &sm[(32 * w + 8 * t) * 64]);
        gl_lds16(&WqkvT[(size_t)(n0 + r) * 1024 + c_log * 8],
                 &sm[8192 + (32 * w + 8 * t) * 64]);
    }
    __syncthreads();
    int cur = 0;
    for (int kt = 0; kt < 16; ++kt) {
        bf16* At = sm + cur * 16384;
        bf16* Bt = At + 8192;
        if (kt + 1 < 16) {
            bf16* Atn = sm + (cur ^ 1) * 16384;
            bf16* Btn = Atn + 8192;
            int k0 = (kt + 1) * 64;
            #pragma unroll
            for (int t = 0; t < 4; ++t) {
                int r = 32 * w + 8 * t + lr;
                gl_lds16(&xb[(size_t)(m0 + r) * 1024 + k0 + c_log * 8],
                         &Atn[(32 * w + 8 * t) * 64]);
                gl_lds16(&WqkvT[(size_t)(n0 + r) * 1024 + k0 + c_log * 8],
                         &Btn[(32 * w + 8 * t) * 64]);
            }
        }
        bf16x8 af[2][4], bfr[2][4];
        #pragma unroll
        for (int ks = 0; ks < 2; ++ks)
            #pragma unroll
            for (int s = 0; s < 4; ++s) {
                int ra = 64 * wm + 16 * s + ln15;
                af[ks][s]  = *(const bf16x8*)&At[(ra * 8 + ((4 * ks + q) ^ (ra & 7))) * 8];
                int rb = 64 * wn + 16 * s + ln15;
                bfr[ks][s] = *(const bf16x8*)&Bt[(rb * 8 + ((4 * ks + q) ^ (rb & 7))) * 8];
            }
        #pragma unroll
        for (int ks = 0; ks < 2; ++ks)
            #pragma unroll
            for (int si = 0; si < 4; ++si)
                #pragma unroll
                for (int sj = 0; sj < 4; ++sj)
                    acc[si][sj] = __builtin_amdgcn_mfma_f32_16x16x32_bf16(
                        af[ks][si], bfr[ks][sj], acc[si][sj], 0, 0, 0);
        __syncthreads();
        cur ^= 1;
    }

    if (bx < 16) {
        // q (pre-scaled) / k natural layout
        const float QSCL = 0.125f * 1.44269504088896341f;
        #pragma unroll
        for (int si = 0; si < 4; ++si)
            #pragma unroll
            for (int sj = 0; sj < 4; ++sj)
                #pragma unroll
                for (int r = 0; r < 4; ++r) {
                    int row = m0 + 64 * wm + 16 * si + 4 * q + r;
                    int col = n0 + 64 * wn + 16 * sj + ln15;
                    float v = acc[si][sj][r] + (col < 1024 ? bq[col] : bkv[col - 1024]);
                    if (col < 1024) qbuf[(size_t)row * 1024 + col] = (bf16)(v * QSCL);
                    else            kbuf[(size_t)row * 1024 + (col - 1024)] = (bf16)v;
                }
    } else {
        // V: transpose to (b,h,d,t) via LDS bounce (aliases staging buffers;
        // the loop's final barrier guarantees all reads are done)
        #pragma unroll
        for (int si = 0; si < 4; ++si)
            #pragma unroll
            for (int sj = 0; sj < 4; ++sj) {
                int dL = 64 * wn + 16 * sj + ln15;        // 0..127
                int tL = 64 * wm + 16 * si + 4 * q;       // +r
                float bias = bkv[1024 + (bx - 16) * 128 + dL];
                bf16x4 o4;
                #pragma unroll
                for (int r = 0; r < 4; ++r)
                    o4[r] = (bf16)(acc[si][sj][r] + bias);
                *(bf16x4*)&sm[dL * 132 + tL] = o4;
            }
        __syncthreads();
        const int b = m0 >> 11;
        const int t0 = m0 & 2047;
        const int h0 = (bx - 16) * 2;
        #pragma unroll
        for (int p = 0; p < 16; ++p) {
            int d = (tid >> 5) + 8 * p;
            int t = (tid & 31) * 4;
            bf16x4 v4 = *(const bf16x4*)&sm[d * 132 + t];
            int rowv = (b * NHEAD + h0 + (d >> 6)) * DH + (d & 63);
            *(bf16x4*)&vtbuf[(size_t)rowv * SEQ_N + t0 + t] = v4;
        }
    }
}

// ---------------------------------------------------------------------------
// MFMA flash attention — EXACT R6/R11 best (88 us). Untouched.
// ---------------------------------------------------------------------------
__global__ __launch_bounds__(256, 4) void attn_mfma_kernel(
    const bf16* __restrict__ qb,    // [4096][1024], pre-scaled
    const bf16* __restrict__ kb,    // [4096][1024]
    const bf16* __restrict__ vt,    // [(b,h,d)][2048]
    const bf16* __restrict__ pfrag, // fragment-ready p
    bf16* __restrict__ ob,          // [4096][1024]
    float* __restrict__ Opart,      // [1024][64][64] fp32 partials
    float2* __restrict__ MLpart)    // [1024][64] (m,l)
{
    const int f   = (int)blockIdx.x;   // 0..1535
    const int xcd = f & 7;
    const int jj  = f >> 3;            // 0..191
    const int s   = jj >> 2;           // 0..47, ascending == length descending
    const int bh  = xcd * 4 + (jj & 3);
    int qblk, lo, hi, part;            // part: -1 single, 0/1 split halves
    if (s < 16) { qblk = 16 + s; lo = 0; hi = 16; part = 0; }
    else {
        int k = (s - 16) >> 1;
        if (((s - 16) & 1) == 0) { qblk = 31 - k; lo = 16; hi = qblk + 1; part = 1; }
        else                     { qblk = 15 - k; lo = 0;  hi = qblk + 1; part = -1; }
    }
    const int bi = bh >> 4, hh = bh & 15;
    const int i0 = qblk << 6;
    const int tid = threadIdx.x, w = tid >> 6, lane = tid & 63;
    const int q = lane >> 4, ln15 = lane & 15;
    const int lr = lane >> 3, c_log = (lane & 7) ^ lr;

    __shared__ __align__(16) bf16 smem[17664];
    bf16* S2L = smem + w * 1344;           // per-wave 16 x 84   [0,5376)
    bf16* Ks  = smem + 5376;               // 64x64 swizzled
    bf16* Vs  = smem + 9472;               // 64x64 swizzled
    bf16* Pw  = smem + 13568 + w * 1024;   // per-wave 16 x 64

    const bf16* qbase = qb + ((size_t)(bi * SEQ_N + i0)) * DIM + hh * DH;
    const bf16* kbase = kb + ((size_t)bi * SEQ_N) * DIM + hh * DH;
    const bf16* vbase = vt + ((size_t)(bi * NHEAD + hh) * DH) * SEQ_N;

    bf16x8 qf0 = *(const bf16x8*)&qbase[(size_t)(16 * w + ln15) * DIM + q * 8];
    bf16x8 qf1 = *(const bf16x8*)&qbase[(size_t)(16 * w + ln15) * DIM + 32 + q * 8];

    const int A0 = 127 - 4 * qblk - w;
    f32x4 s2r4;
    {
        int sb0 = A0 + 4 * lo;
        bf16x8 f0 = *(const bf16x8*)&pfrag[(((size_t)sb0 * 2 + 0) * 64 + lane) * 8];
        bf16x8 f1 = *(const bf16x8*)&pfrag[(((size_t)sb0 * 2 + 1) * 64 + lane) * 8];
        f32x4 a = {0.f, 0.f, 0.f, 0.f};
        a = __builtin_amdgcn_mfma_f32_16x16x32_bf16(f0, qf0, a, 0, 0, 0);
        a = __builtin_amdgcn_mfma_f32_16x16x32_bf16(f1, qf1, a, 0, 0, 0);
        s2r4 = a;
    }

    float m_run = -1e30f, l_run = 0.f;
    f32x4 O_T[4] = {};

    for (int jt = lo; jt < hi; ++jt) {
        const int j0 = jt << 6;

        bf16x8 pfA[4][2];
        #pragma unroll
        for (int ss = 1; ss <= 4; ++ss) {
            int sb = A0 + 4 * jt + ss;
            if (sb > 127) sb = 127;
            pfA[ss-1][0] = *(const bf16x8*)&pfrag[(((size_t)sb * 2 + 0) * 64 + lane) * 8];
            pfA[ss-1][1] = *(const bf16x8*)&pfrag[(((size_t)sb * 2 + 1) * 64 + lane) * 8];
        }
        #pragma unroll
        for (int t = 0; t < 2; ++t) {
            int r = 16 * w + 8 * t + lr;
            gl_lds16(kbase + (size_t)(j0 + r) * DIM + c_log * 8,
                     &Ks[(16 * w + 8 * t) * 64]);
            gl_lds16(vbase + (size_t)r * SEQ_N + j0 + c_log * 8,
                     &Vs[(16 * w + 8 * t) * 64]);
        }

        {
            f32x4 s2r[5];
            s2r[0] = s2r4;
            #pragma unroll
            for (int ss = 1; ss <= 4; ++ss) {
                f32x4 a = {0.f, 0.f, 0.f, 0.f};
                a = __builtin_amdgcn_mfma_f32_16x16x32_bf16(pfA[ss-1][0], qf0, a, 0, 0, 0);
                a = __builtin_amdgcn_mfma_f32_16x16x32_bf16(pfA[ss-1][1], qf1, a, 0, 0, 0);
                s2r[ss] = a;
            }
            s2r4 = s2r[4];
            #pragma unroll
            for (int ss = 0; ss < 5; ++ss)
                #pragma unroll
                for (int r = 0; r < 4; ++r)
                    S2L[ln15 * 84 + 16 * ss + 4 * q + r] = (bf16)s2r[ss][r];
        }

        __syncthreads();

        float sv[4][4];
        __builtin_amdgcn_s_setprio(1);
        #pragma unroll
        for (int sn = 0; sn < 4; ++sn) {
            int rk = 16 * sn + ln15;
            bf16x8 k0f = *(const bf16x8*)&Ks[(rk * 8 + ((q    ) ^ (rk & 7))) * 8];
            bf16x8 k1f = *(const bf16x8*)&Ks[(rk * 8 + ((4 + q) ^ (rk & 7))) * 8];
            f32x4 a;
            #pragma unroll
            for (int r = 0; r < 4; ++r)
                a[r] = (float)S2L[ln15 * 84 + 15 - ln15 + 16 * sn + 4 * q + r];
            a = __builtin_amdgcn_mfma_f32_16x16x32_bf16(k0f, qf0, a, 0, 0, 0);
            a = __builtin_amdgcn_mfma_f32_16x16x32_bf16(k1f, qf1, a, 0, 0, 0);
            #pragma unroll
            for (int r = 0; r < 4; ++r)
                sv[sn][r] = a[r];
        }
        __builtin_amdgcn_s_setprio(0);
        if (jt == qblk) {
            #pragma unroll
            for (int sn = 0; sn < 4; ++sn)
                #pragma unroll
                for (int r = 0; r < 4; ++r)
                    if (16 * sn + 4 * q + r > 16 * w + ln15)
                        sv[sn][r] = -1e30f;
        }

        float mx = sv[0][0];
        #pragma unroll
        for (int sn = 0; sn < 4; ++sn)
            #pragma unroll
            for (int r = 0; r < 4; ++r)
                mx = fmaxf(mx, sv[sn][r]);
        mx = fmaxf(mx, __shfl_xor(mx, 16));
        mx = fmaxf(mx, __shfl_xor(mx, 32));
        const float mn = fmaxf(m_run, mx);
        float sum = 0.f;
        #pragma unroll
        for (int sn = 0; sn < 4; ++sn)
            #pragma unroll
            for (int r = 0; r < 4; ++r) {
                float e = exp2f(sv[sn][r] - mn);
                sv[sn][r] = e;
                sum += e;
            }
        sum += __shfl_xor(sum, 16);
        sum += __shfl_xor(sum, 32);
        if (__all(mx <= m_run)) {
            l_run += sum;                       // alpha == 1 exactly
        } else {
            const float alpha = exp2f(m_run - mn);
            l_run = l_run * alpha + sum;
            #pragma unroll
            for (int sd = 0; sd < 4; ++sd)
                #pragma unroll
                for (int r = 0; r < 4; ++r)
                    O_T[sd][r] *= alpha;
        }
        m_run = mn;

        #pragma unroll
        for (int sn = 0; sn < 4; ++sn)
            #pragma unroll
            for (int r = 0; r < 4; ++r) {
                int chunk = (2 * sn + (q >> 1)) ^ (ln15 & 7);
                Pw[ln15 * 64 + chunk * 8 + 4 * (q & 1) + r] = (bf16)sv[sn][r];
            }

        __builtin_amdgcn_s_waitcnt(0);

        __builtin_amdgcn_s_setprio(1);
        #pragma unroll
        for (int ks = 0; ks < 2; ++ks) {
            bf16x8 pT = *(const bf16x8*)&Pw[ln15 * 64 + (((4 * ks + q) ^ (ln15 & 7))) * 8];
            #pragma unroll
            for (int sd = 0; sd < 4; ++sd) {
                int rv = 16 * sd + ln15;
                bf16x8 vf = *(const bf16x8*)&Vs[(rv * 8 + ((4 * ks + q) ^ (rv & 7))) * 8];
                O_T[sd] = __builtin_amdgcn_mfma_f32_16x16x32_bf16(vf, pT, O_T[sd], 0, 0, 0);
            }
        }
        __builtin_amdgcn_s_setprio(0);
        __syncthreads();
    }

    const int row = 16 * w + ln15;
    if (part < 0) {
        const float inv = 1.0f / l_run;
        const size_t grow = (size_t)bi * SEQ_N + i0 + row;
        #pragma unroll
        for (int sd = 0; sd < 4; ++sd) {
            bf16x4 o4;
            #pragma unroll
            for (int r = 0; r < 4; ++r)
                o4[r] = (bf16)(O_T[sd][r] * inv);
            *(bf16x4*)&ob[grow * DIM + hh * DH + 16 * sd + 4 * q] = o4;
        }
    } else {
        const int slot = (bh * 16 + (qblk - 16)) * 2 + part;
        float* op = Opart + (size_t)slot * 4096 + row * 64;
        #pragma unroll
        for (int sd = 0; sd < 4; ++sd)
            *(f32x4*)&op[16 * sd + 4 * q] = O_T[sd];
        if (lane < 16)
            MLpart[slot * 64 + row] = make_float2(m_run, l_run);
    }
}

// ---------------------------------------------------------------------------
// merge: combine the two KV-half partials of each qblk>=16 row-block.
// ---------------------------------------------------------------------------
__global__ __launch_bounds__(256) void merge_kernel(
    const float* __restrict__ Opart, const float2* __restrict__ MLpart,
    bf16* __restrict__ ob)
{
    const int pb = blockIdx.x;             // 0..511
    const int bh = pb >> 4, qblk = 16 + (pb & 15);
    const int bi = bh >> 4, hh = bh & 15;
    const int row = threadIdx.x >> 2;
    const int d0 = (threadIdx.x & 3) * 16;

    float2 ml0 = MLpart[(pb * 2 + 0) * 64 + row];
    float2 ml1 = MLpart[(pb * 2 + 1) * 64 + row];
    float m = fmaxf(ml0.x, ml1.x);
    float a0 = exp2f(ml0.x - m), a1 = exp2f(ml1.x - m);
    float inv = 1.0f / (ml0.y * a0 + ml1.y * a1);

    const float* o0 = Opart + ((size_t)(pb * 2 + 0)) * 4096 + row * 64 + d0;
    const float* o1 = Opart + ((size_t)(pb * 2 + 1)) * 4096 + row * 64 + d0;
    bf16* dst = ob + ((size_t)(bi * SEQ_N + qblk * 64 + row)) * DIM + hh * DH + d0;
    #pragma unroll
    for (int k = 0; k < 4; ++k) {
        float4 v0 = *(const float4*)&o0[4 * k];
        float4 v1 = *(const float4*)&o1[4 * k];
        bf16x4 o4;
        o4[0] = (bf16)((v0.x * a0 + v1.x * a1) * inv);
        o4[1] = (bf16)((v0.y * a0 + v1.y * a1) * inv);
        o4[2] = (bf16)((v0.z * a0 + v1.z * a1) * inv);
        o4[3] = (bf16)((v0.w * a0 + v1.w * a1) * inv);
        *(bf16x4*)&dst[4 * k] = o4;
    }
}

// ---------------------------------------------------------------------------
// out = abuf @ WoT^T + bo, fp32 out. 128x64 tiles, grid (16,32).
// Same T3 2-phase pipeline: dbuf LDS (48 KB), stage-early, 1 barrier/K-step.
// ---------------------------------------------------------------------------
__global__ __launch_bounds__(256) void outproj_kernel(
    const bf16* __restrict__ ab, const bf16* __restrict__ WoT,
    const float* __restrict__ bo, float* __restrict__ out)
{
    __shared__ __align__(16) bf16 sm[24576];   // 2 x (At 8192 | Bt 4096)
    const int tid = threadIdx.x, w = tid >> 6, lane = tid & 63;
    const int q = lane >> 4, ln15 = lane & 15;
    const int lr = lane >> 3, c_log = (lane & 7) ^ lr;
    const int m0 = blockIdx.y * 128, n0 = blockIdx.x * 64;

    f32x4 acc[2][4] = {};
    // prologue: stage tile 0 into buf0
    #pragma unroll
    for (int t = 0; t < 4; ++t)
        gl_lds16(&ab[(size_t)(m0 + 32 * w + 8 * t + lr) * 1024 + c_log * 8],
                 &sm[(32 * w + 8 * t) * 64]);
    #pragma unroll
    for (int t = 0; t < 2; ++t)
        gl_lds16(&WoT[(size_t)(n0 + 16 * w + 8 * t + lr) * 1024 + c_log * 8],
                 &sm[8192 + (16 * w + 8 * t) * 64]);
    __syncthreads();
    int cur = 0;
    for (int kt = 0; kt < 16; ++kt) {
        bf16* At = sm + cur * 12288;
        bf16* Bt = At + 8192;
        if (kt + 1 < 16) {
            bf16* Atn = sm + (cur ^ 1) * 12288;
            bf16* Btn = Atn + 8192;
            int k0 = (kt + 1) * 64;
            #pragma unroll
            for (int t = 0; t < 4; ++t)
                gl_lds16(&ab[(size_t)(m0 + 32 * w + 8 * t + lr) * 1024 + k0 + c_log * 8],
                         &Atn[(32 * w + 8 * t) * 64]);
            #pragma unroll
            for (int t = 0; t < 2; ++t)
                gl_lds16(&WoT[(size_t)(n0 + 16 * w + 8 * t + lr) * 1024 + k0 + c_log * 8],
                         &Btn[(16 * w + 8 * t) * 64]);
        }
        bf16x8 bfr[2][4];
        #pragma unroll
        for (int ks = 0; ks < 2; ++ks)
            #pragma unroll
            for (int sn = 0; sn < 4; ++sn) {
                int rb = 16 * sn + ln15;
                bfr[ks][sn] = *(const bf16x8*)&Bt[(rb * 8 + ((4 * ks + q) ^ (rb & 7))) * 8];
            }
        #pragma unroll
        for (int sm2 = 0; sm2 < 2; ++sm2) {
            int ra = 32 * w + 16 * sm2 + ln15;
            #pragma unroll
            for (int ks = 0; ks < 2; ++ks) {
                bf16x8 af = *(const bf16x8*)&At[(ra * 8 + ((4 * ks + q) ^ (ra & 7))) * 8];
                #pragma unroll
                for (int sn = 0; sn < 4; ++sn)
                    acc[sm2][sn] = __builtin_amdgcn_mfma_f32_16x16x32_bf16(
                        af, bfr[ks][sn], acc[sm2][sn], 0, 0, 0);
            }
        }
        __syncthreads();
        cur ^= 1;
    }
    #pragma unroll
    for (int sm2 = 0; sm2 < 2; ++sm2)
        #pragma unroll
        for (int sn = 0; sn < 4; ++sn) {
            int col = n0 + 16 * sn + ln15;
            float bias = bo[col];
            #pragma unroll
            for (int r = 0; r < 4; ++r) {
                int row = m0 + 32 * w + 16 * sm2 + 4 * q + r;
                out[(size_t)row * 1024 + col] = acc[sm2][sn][r] + bias;
            }
        }
}

// ---------------------------------------------------------------------------
extern "C" void kernel_launch(void* const* d_in, const int* in_sizes, int n_in,
                              void* d_out, int out_size, void* d_ws, size_t ws_size,
                              hipStream_t stream)
{
    const float* x    = (const float*)d_in[0];
    const float* pos  = (const float*)d_in[1];
    const float* Wq   = (const float*)d_in[2];
    const float* bq   = (const float*)d_in[3];
    const float* Wkv  = (const float*)d_in[4];
    const float* bkv  = (const float*)d_in[5];
    const float* Wp   = (const float*)d_in[6];
    const float* bp   = (const float*)d_in[7];
    const float* Wo   = (const float*)d_in[8];
    const float* bo   = (const float*)d_in[9];
    float* out = (float*)d_out;

    const int M = 2 * SEQ_N;   // 4096
    char* ws = (char*)d_ws;
    bf16* xb     = (bf16*)ws;  ws += (size_t)M * DIM * 2;          //  8 MB
    bf16* posb   = (bf16*)ws;  ws += (size_t)SEQ_N * DIM * 2;      //  4 MB
    bf16* WqkvT  = (bf16*)ws;  ws += (size_t)3072 * 1024 * 2;      //  6 MB
    bf16* WoT    = (bf16*)ws;  ws += (size_t)DIM * DIM * 2;        //  2 MB
    bf16* WpT    = (bf16*)ws;  ws += (size_t)DH * DIM * 2;
    bf16* qbuf   = (bf16*)ws;  ws += (size_t)M * DIM * 2;
    bf16* kbuf   = (bf16*)ws;  ws += (size_t)M * DIM * 2;
    bf16* vtbuf  = (bf16*)ws;  ws += (size_t)M * DIM * 2;
    bf16* pfrag  = (bf16*)ws;  ws += (size_t)512 * 1024;
    bf16* abuf   = (bf16*)ws;

    // attn partials alias xb/posb/WqkvT (dead after qkvp):
    // Opart 1024*64*64*4 = 16 MB, MLpart 1024*64*8 = 0.5 MB  (< 18 MB region)
    float*  Opart  = (float*)d_ws;
    float2* MLpart = (float2*)((char*)d_ws + (size_t)1024 * 4096 * 4);

    dim3 blk(256);
    prep_kernel<<<dim3(10304), blk, 0, stream>>>(
        x, pos, Wq, Wkv, Wo, Wp, xb, posb, WqkvT, WoT, WpT);

    qkvp_kernel<<<dim3(25, 32), blk, 0, stream>>>(
        xb, WqkvT, posb, WpT, bq, bkv, bp, qbuf, kbuf, vtbuf, pfrag);

    attn_mfma_kernel<<<dim3(1536), blk, 0, stream>>>(
        qbuf, kbuf, vtbuf, pfrag, abuf, Opart, MLpart);

    merge_kernel<<<dim3(512), blk, 0, stream>>>(Opart, MLpart, abuf);

    outproj_kernel<<<dim3(16, 32), blk, 0, stream>>>(
        abuf, WoT, bo, out);
}